// Round 1
// baseline (11497.926 us; speedup 1.0000x reference)
//
#include <hip/hip_runtime.h>
#include <math.h>

#define BATCH   64
#define DIMC    384
#define KEY_DIM 16
#define HEADS   8
#define DD      64      // per-head value dim
#define DH      512
#define NH_KD   128
#define RES     28
#define RES2    14
#define NN      784
#define NN2     196
#define OUT_DIM 384
#define SCALE   0.25f

// ---------------- qin = dwconv3x3 stride2 (pad 1) + pool (x[::2,::2]) ----------------
__global__ void qin_kernel(const float* __restrict__ x, const float* __restrict__ ql_w,
                           const float* __restrict__ ql_b, float* __restrict__ qin) {
    int c = blockIdx.x;           // 0..383
    int b = blockIdx.y;           // 0..63
    int n2 = threadIdx.x;
    if (n2 >= NN2) return;
    int i = n2 / RES2, j = n2 % RES2;
    const float* xp = x + ((size_t)b * DIMC + c) * (RES * RES);
    const float* w  = ql_w + c * 9;
    float acc = ql_b[c];
    #pragma unroll
    for (int di = 0; di < 3; ++di) {
        int r = 2 * i + di - 1;
        if (r < 0 || r >= RES) continue;
        #pragma unroll
        for (int dj = 0; dj < 3; ++dj) {
            int cc = 2 * j + dj - 1;
            if (cc < 0 || cc >= RES) continue;
            acc += xp[r * RES + cc] * w[di * 3 + dj];
        }
    }
    acc += xp[(2 * i) * RES + 2 * j];   // pool_q
    qin[((size_t)b * DIMC + c) * NN2 + n2] = acc;
}

// ---------------- generic conv1x1 + bn: out[b,o,n] = s[o]*(sum_c in[b,c,n]*w[o,c]+bias[o])+off[o]
__global__ void conv1x1_bn_kernel(const float* __restrict__ in, const float* __restrict__ w,
                                  const float* __restrict__ bias, const float* __restrict__ s,
                                  const float* __restrict__ off, float* __restrict__ out,
                                  int C, int Nn) {
    int n  = blockIdx.x * blockDim.x + threadIdx.x;
    int oc = blockIdx.y;
    int b  = blockIdx.z;
    int O  = gridDim.y;
    if (n >= Nn) return;
    const float* inp = in + (size_t)b * C * Nn;
    const float* wp  = w + (size_t)oc * C;
    float acc = 0.f;
    for (int c = 0; c < C; ++c)
        acc += inp[(size_t)c * Nn + n] * wp[c];
    acc = (acc + bias[oc]) * s[oc] + off[oc];
    out[((size_t)b * O + oc) * Nn + n] = acc;
}

// ---------------- v_local = bn(dwconv3x3 stride2 (pad 1) over v) ----------------
__global__ void vlocal_kernel(const float* __restrict__ v, const float* __restrict__ vl_w,
                              const float* __restrict__ vl_b, const float* __restrict__ vl_s,
                              const float* __restrict__ vl_o, float* __restrict__ vlocal) {
    int c = blockIdx.x;           // 0..511
    int b = blockIdx.y;
    int n2 = threadIdx.x;
    if (n2 >= NN2) return;
    int i = n2 / RES2, j = n2 % RES2;
    const float* vp = v + ((size_t)b * DH + c) * NN;
    const float* w  = vl_w + c * 9;
    float acc = vl_b[c];
    #pragma unroll
    for (int di = 0; di < 3; ++di) {
        int r = 2 * i + di - 1;
        if (r < 0 || r >= RES) continue;
        #pragma unroll
        for (int dj = 0; dj < 3; ++dj) {
            int cc = 2 * j + dj - 1;
            if (cc < 0 || cc >= RES) continue;
            acc += vp[r * RES + cc] * w[di * 3 + dj];
        }
    }
    vlocal[((size_t)b * DH + c) * NN2 + n2] = acc * vl_s[c] + vl_o[c];
}

// ---------------- attention: one block per (b, h, query) ----------------
__global__ void attn_kernel(const float* __restrict__ q, const float* __restrict__ k,
                            const float* __restrict__ v, const float* __restrict__ ab,
                            const int* __restrict__ bias_idxs, float* __restrict__ attnout,
                            int n_off) {
    int n2 = blockIdx.x;          // query 0..195
    int h  = blockIdx.y;
    int b  = blockIdx.z;
    int t  = threadIdx.x;         // 0..255

    __shared__ float qs[KEY_DIM];
    __shared__ float p[NN];
    __shared__ float red[256];
    __shared__ float psum[4][DD];

    if (t < KEY_DIM)
        qs[t] = q[((size_t)b * NH_KD + h * KEY_DIM + t) * NN2 + n2];
    __syncthreads();

    const float* kp  = k + ((size_t)b * NH_KD + h * KEY_DIM) * NN;
    const float* abp = ab + (size_t)h * n_off;
    const int*   bi  = bias_idxs + (size_t)n2 * NN;

    float lmax = -INFINITY;
    for (int key = t; key < NN; key += 256) {
        float acc = 0.f;
        #pragma unroll
        for (int c = 0; c < KEY_DIM; ++c)
            acc += qs[c] * kp[(size_t)c * NN + key];
        acc = acc * SCALE + abp[bi[key]];
        p[key] = acc;
        lmax = fmaxf(lmax, acc);
    }
    red[t] = lmax; __syncthreads();
    for (int s = 128; s > 0; s >>= 1) {
        if (t < s) red[t] = fmaxf(red[t], red[t + s]);
        __syncthreads();
    }
    float m = red[0];
    __syncthreads();

    float lsum = 0.f;
    for (int key = t; key < NN; key += 256) {
        float e = expf(p[key] - m);
        p[key] = e;
        lsum += e;
    }
    red[t] = lsum; __syncthreads();
    for (int s = 128; s > 0; s >>= 1) {
        if (t < s) red[t] += red[t + s];
        __syncthreads();
    }
    float inv = 1.f / red[0];
    __syncthreads();

    // PV: out[d] = sum_key p[key] * v[b, h*64+d, key]
    const float* vp = v + ((size_t)b * DH + h * DD) * NN;
    int d = t & 63;
    int part = t >> 6;            // 0..3, each part covers 196 keys
    float acc = 0.f;
    int k0 = part * 196, k1 = k0 + 196;
    for (int key = k0; key < k1; ++key)
        acc += p[key] * vp[(size_t)d * NN + key];
    psum[part][d] = acc;
    __syncthreads();
    if (t < DD) {
        float r = (psum[0][t] + psum[1][t] + psum[2][t] + psum[3][t]) * inv;
        attnout[((size_t)b * DH + h * DD + t) * NN2 + n2] = r;
    }
}

// ---------------- g = gelu(attnout + vlocal), exact erf gelu ----------------
__global__ void gelu_add_kernel(const float* __restrict__ a, const float* __restrict__ vl,
                                float* __restrict__ g, int total) {
    int i = blockIdx.x * blockDim.x + threadIdx.x;
    if (i >= total) return;
    float x = a[i] + vl[i];
    g[i] = 0.5f * x * (1.f + erff(x * 0.70710678118654752440f));
}

extern "C" void kernel_launch(void* const* d_in, const int* in_sizes, int n_in,
                              void* d_out, int out_size, void* d_ws, size_t ws_size,
                              hipStream_t stream) {
    const float* x     = (const float*)d_in[0];
    const float* ql_w  = (const float*)d_in[1];
    const float* ql_b  = (const float*)d_in[2];
    const float* qp_w  = (const float*)d_in[3];
    const float* qp_b  = (const float*)d_in[4];
    const float* qp_s  = (const float*)d_in[5];
    const float* qp_o  = (const float*)d_in[6];
    const float* k_w   = (const float*)d_in[7];
    const float* k_b   = (const float*)d_in[8];
    const float* k_s   = (const float*)d_in[9];
    const float* k_o   = (const float*)d_in[10];
    const float* v_w   = (const float*)d_in[11];
    const float* v_b   = (const float*)d_in[12];
    const float* v_s   = (const float*)d_in[13];
    const float* v_o   = (const float*)d_in[14];
    const float* vl_w  = (const float*)d_in[15];
    const float* vl_b  = (const float*)d_in[16];
    const float* vl_s  = (const float*)d_in[17];
    const float* vl_o  = (const float*)d_in[18];
    const float* p_w   = (const float*)d_in[19];
    const float* p_b   = (const float*)d_in[20];
    const float* p_s   = (const float*)d_in[21];
    const float* p_o   = (const float*)d_in[22];
    const float* ab    = (const float*)d_in[23];
    const int*   bidx  = (const int*)d_in[24];
    float* out = (float*)d_out;

    int n_off = in_sizes[23] / HEADS;

    float* ws = (float*)d_ws;
    float* qin     = ws;                                   // 64*384*196
    float* qbuf    = qin    + (size_t)BATCH * DIMC * NN2;  // 64*128*196
    float* kbuf    = qbuf   + (size_t)BATCH * NH_KD * NN2; // 64*128*784
    float* vbuf    = kbuf   + (size_t)BATCH * NH_KD * NN;  // 64*512*784
    float* vlocal  = vbuf   + (size_t)BATCH * DH * NN;     // 64*512*196
    float* attnout = vlocal + (size_t)BATCH * DH * NN2;    // 64*512*196
    float* g       = kbuf;                                 // reuse k region (6.42M >= 6.42M)

    // 1. qin
    qin_kernel<<<dim3(DIMC, BATCH), 256, 0, stream>>>(x, ql_w, ql_b, qin);
    // 2. q = bn(1x1(qin))
    conv1x1_bn_kernel<<<dim3(1, NH_KD, BATCH), 256, 0, stream>>>(qin, qp_w, qp_b, qp_s, qp_o, qbuf, DIMC, NN2);
    // 3. k = bn(1x1(x))
    conv1x1_bn_kernel<<<dim3(4, NH_KD, BATCH), 256, 0, stream>>>(x, k_w, k_b, k_s, k_o, kbuf, DIMC, NN);
    // 4. v = bn(1x1(x))
    conv1x1_bn_kernel<<<dim3(4, DH, BATCH), 256, 0, stream>>>(x, v_w, v_b, v_s, v_o, vbuf, DIMC, NN);
    // 5. v_local
    vlocal_kernel<<<dim3(DH, BATCH), 256, 0, stream>>>(vbuf, vl_w, vl_b, vl_s, vl_o, vlocal);
    // 6. attention
    attn_kernel<<<dim3(NN2, HEADS, BATCH), 256, 0, stream>>>(qbuf, kbuf, vbuf, ab, bidx, attnout, n_off);
    // 7. g = gelu(attnout + vlocal)
    {
        int total = BATCH * DH * NN2;
        gelu_add_kernel<<<(total + 255) / 256, 256, 0, stream>>>(attnout, vlocal, g, total);
    }
    // 8. out = bn(1x1(g))
    conv1x1_bn_kernel<<<dim3(1, OUT_DIM, BATCH), 256, 0, stream>>>(g, p_w, p_b, p_s, p_o, out, DH, NN2);
}

// Round 2
// 2801.626 us; speedup vs baseline: 4.1040x; 4.1040x over previous
//
#include <hip/hip_runtime.h>
#include <math.h>

#define BATCH   64
#define DIMC    384
#define KEY_DIM 16
#define HEADS   8
#define DD      64      // per-head value dim
#define DH      512
#define NH_KD   128
#define RES     28
#define RES2    14
#define NN      784
#define NN2     196
#define OUT_DIM 384
#define SCALE   0.25f

typedef __attribute__((ext_vector_type(8))) short bf16x8;
typedef __attribute__((ext_vector_type(4))) float f32x4;

__device__ inline short f2bf(float f) {
    unsigned u = __float_as_uint(f);
    unsigned r = (u + 0x7fff + ((u >> 16) & 1)) >> 16;
    return (short)r;
}
__device__ inline float bf2f(short h) {
    return __uint_as_float(((unsigned)(unsigned short)h) << 16);
}

// ---------------- qin = dwconv3x3 stride2 (pad 1) + pool (x[::2,::2]) ----------------
__global__ void qin_kernel(const float* __restrict__ x, const float* __restrict__ ql_w,
                           const float* __restrict__ ql_b, float* __restrict__ qin) {
    int c = blockIdx.x;
    int b = blockIdx.y;
    int n2 = threadIdx.x;
    if (n2 >= NN2) return;
    int i = n2 / RES2, j = n2 % RES2;
    const float* xp = x + ((size_t)b * DIMC + c) * (RES * RES);
    const float* w  = ql_w + c * 9;
    float acc = ql_b[c];
    #pragma unroll
    for (int di = 0; di < 3; ++di) {
        int r = 2 * i + di - 1;
        if (r < 0 || r >= RES) continue;
        #pragma unroll
        for (int dj = 0; dj < 3; ++dj) {
            int cc = 2 * j + dj - 1;
            if (cc < 0 || cc >= RES) continue;
            acc += xp[r * RES + cc] * w[di * 3 + dj];
        }
    }
    acc += xp[(2 * i) * RES + 2 * j];
    qin[((size_t)b * DIMC + c) * NN2 + n2] = acc;
}

// ---------------- MFMA conv1x1 + bn  (split-bf16 for near-fp32 accuracy) ----------------
// out[b,o,n] = s[o]*(sum_c in[b,c,n]*w[o,c] + bias[o]) + off[o]
// grid: (ceil(Nn/64), O/64, BATCH), block 256 (4 waves, 2x2 of 32x32)
__global__ __launch_bounds__(256)
void conv1x1_mfma_kernel(const float* __restrict__ in, const float* __restrict__ w,
                         const float* __restrict__ bias, const float* __restrict__ s,
                         const float* __restrict__ off, float* __restrict__ out,
                         int C, int Nn) {
    __shared__ __align__(16) short Ahi[64][40];
    __shared__ __align__(16) short Alo[64][40];
    __shared__ __align__(16) short Bhi[64][40];
    __shared__ __align__(16) short Blo[64][40];

    const int t = threadIdx.x;
    const int n_base = blockIdx.x * 64;
    const int o_base = blockIdx.y * 64;
    const int b = blockIdx.z;
    const int O = gridDim.y * 64;
    const float* inb = in + (size_t)b * C * Nn;

    const int lane = t & 63;
    const int wid  = t >> 6;
    const int wm   = wid & 1;        // wave row (0..1)
    const int wn   = wid >> 1;       // wave col (0..1)
    const int lr   = lane & 15;      // row/col within 16
    const int kg   = lane >> 4;      // k-group 0..3

    f32x4 acc[2][2];
    #pragma unroll
    for (int m = 0; m < 2; ++m)
        #pragma unroll
        for (int n = 0; n < 2; ++n)
            acc[m][n] = (f32x4){0.f, 0.f, 0.f, 0.f};

    // staging coords
    const int a_c = t & 31, a_o = t >> 5;        // A: 8 rows per thread
    const int b_n = t & 63, b_c = t >> 6;        // B: 8 k-rows per thread
    const int gn = n_base + b_n;
    const bool nok = (gn < Nn);

    for (int k0 = 0; k0 < C; k0 += 32) {
        // stage A (weights) [64 o][32 c]
        #pragma unroll
        for (int i = 0; i < 8; ++i) {
            int row = a_o + i * 8;
            float wv = w[(size_t)(o_base + row) * C + k0 + a_c];
            short h = f2bf(wv);
            Ahi[row][a_c] = h;
            Alo[row][a_c] = f2bf(wv - bf2f(h));
        }
        // stage B (input, transposed) [64 n][32 c]
        #pragma unroll
        for (int i = 0; i < 8; ++i) {
            int c = b_c + i * 4;
            float v = nok ? inb[(size_t)(k0 + c) * Nn + gn] : 0.f;
            short h = f2bf(v);
            Bhi[b_n][c] = h;
            Blo[b_n][c] = f2bf(v - bf2f(h));
        }
        __syncthreads();

        bf16x8 ah[2], al[2], bh[2], bl[2];
        #pragma unroll
        for (int m = 0; m < 2; ++m) {
            int row = wm * 32 + m * 16 + lr;
            ah[m] = *(const bf16x8*)&Ahi[row][kg * 8];
            al[m] = *(const bf16x8*)&Alo[row][kg * 8];
        }
        #pragma unroll
        for (int n = 0; n < 2; ++n) {
            int row = wn * 32 + n * 16 + lr;
            bh[n] = *(const bf16x8*)&Bhi[row][kg * 8];
            bl[n] = *(const bf16x8*)&Blo[row][kg * 8];
        }
        #pragma unroll
        for (int m = 0; m < 2; ++m)
            #pragma unroll
            for (int n = 0; n < 2; ++n) {
                acc[m][n] = __builtin_amdgcn_mfma_f32_16x16x32_bf16(ah[m], bh[n], acc[m][n], 0, 0, 0);
                acc[m][n] = __builtin_amdgcn_mfma_f32_16x16x32_bf16(ah[m], bl[n], acc[m][n], 0, 0, 0);
                acc[m][n] = __builtin_amdgcn_mfma_f32_16x16x32_bf16(al[m], bh[n], acc[m][n], 0, 0, 0);
            }
        __syncthreads();
    }

    // epilogue: D layout col=lane&15, row=(lane>>4)*4+r
    #pragma unroll
    for (int m = 0; m < 2; ++m) {
        #pragma unroll
        for (int n = 0; n < 2; ++n) {
            int col = n_base + wn * 32 + n * 16 + lr;
            if (col >= Nn) continue;
            #pragma unroll
            for (int r = 0; r < 4; ++r) {
                int row = o_base + wm * 32 + m * 16 + kg * 4 + r;
                float a = s[row];
                float v = acc[m][n][r] * a + (bias[row] * a + off[row]);
                out[((size_t)b * O + row) * Nn + col] = v;
            }
        }
    }
}

// ---------------- v_local = bn(dwconv3x3 stride2 (pad 1) over v) ----------------
__global__ void vlocal_kernel(const float* __restrict__ v, const float* __restrict__ vl_w,
                              const float* __restrict__ vl_b, const float* __restrict__ vl_s,
                              const float* __restrict__ vl_o, float* __restrict__ vlocal) {
    int c = blockIdx.x;
    int b = blockIdx.y;
    int n2 = threadIdx.x;
    if (n2 >= NN2) return;
    int i = n2 / RES2, j = n2 % RES2;
    const float* vp = v + ((size_t)b * DH + c) * NN;
    const float* w  = vl_w + c * 9;
    float acc = vl_b[c];
    #pragma unroll
    for (int di = 0; di < 3; ++di) {
        int r = 2 * i + di - 1;
        if (r < 0 || r >= RES) continue;
        #pragma unroll
        for (int dj = 0; dj < 3; ++dj) {
            int cc = 2 * j + dj - 1;
            if (cc < 0 || cc >= RES) continue;
            acc += vp[r * RES + cc] * w[di * 3 + dj];
        }
    }
    vlocal[((size_t)b * DH + c) * NN2 + n2] = acc * vl_s[c] + vl_o[c];
}

// ---------------- attention: one block per (b, h, query) ----------------
__global__ void attn_kernel(const float* __restrict__ q, const float* __restrict__ k,
                            const float* __restrict__ v, const float* __restrict__ ab,
                            const int* __restrict__ bias_idxs, float* __restrict__ attnout,
                            int n_off) {
    int n2 = blockIdx.x;
    int h  = blockIdx.y;
    int b  = blockIdx.z;
    int t  = threadIdx.x;

    __shared__ float qs[KEY_DIM];
    __shared__ float p[NN];
    __shared__ float red[256];
    __shared__ float psum[4][DD];

    if (t < KEY_DIM)
        qs[t] = q[((size_t)b * NH_KD + h * KEY_DIM + t) * NN2 + n2];
    __syncthreads();

    const float* kp  = k + ((size_t)b * NH_KD + h * KEY_DIM) * NN;
    const float* abp = ab + (size_t)h * n_off;
    const int*   bi  = bias_idxs + (size_t)n2 * NN;

    float lmax = -INFINITY;
    for (int key = t; key < NN; key += 256) {
        float acc = 0.f;
        #pragma unroll
        for (int c = 0; c < KEY_DIM; ++c)
            acc += qs[c] * kp[(size_t)c * NN + key];
        acc = acc * SCALE + abp[bi[key]];
        p[key] = acc;
        lmax = fmaxf(lmax, acc);
    }
    red[t] = lmax; __syncthreads();
    for (int s = 128; s > 0; s >>= 1) {
        if (t < s) red[t] = fmaxf(red[t], red[t + s]);
        __syncthreads();
    }
    float m = red[0];
    __syncthreads();

    float lsum = 0.f;
    for (int key = t; key < NN; key += 256) {
        float e = expf(p[key] - m);
        p[key] = e;
        lsum += e;
    }
    red[t] = lsum; __syncthreads();
    for (int s = 128; s > 0; s >>= 1) {
        if (t < s) red[t] += red[t + s];
        __syncthreads();
    }
    float inv = 1.f / red[0];
    __syncthreads();

    const float* vp = v + ((size_t)b * DH + h * DD) * NN;
    int d = t & 63;
    int part = t >> 6;
    float acc = 0.f;
    int k0 = part * 196, k1 = k0 + 196;
    for (int key = k0; key < k1; ++key)
        acc += p[key] * vp[(size_t)d * NN + key];
    psum[part][d] = acc;
    __syncthreads();
    if (t < DD) {
        float r = (psum[0][t] + psum[1][t] + psum[2][t] + psum[3][t]) * inv;
        attnout[((size_t)b * DH + h * DD + t) * NN2 + n2] = r;
    }
}

// ---------------- g = gelu(attnout + vlocal), exact erf gelu ----------------
__global__ void gelu_add_kernel(const float* __restrict__ a, const float* __restrict__ vl,
                                float* __restrict__ g, int total) {
    int i = blockIdx.x * blockDim.x + threadIdx.x;
    if (i >= total) return;
    float x = a[i] + vl[i];
    g[i] = 0.5f * x * (1.f + erff(x * 0.70710678118654752440f));
}

extern "C" void kernel_launch(void* const* d_in, const int* in_sizes, int n_in,
                              void* d_out, int out_size, void* d_ws, size_t ws_size,
                              hipStream_t stream) {
    const float* x     = (const float*)d_in[0];
    const float* ql_w  = (const float*)d_in[1];
    const float* ql_b  = (const float*)d_in[2];
    const float* qp_w  = (const float*)d_in[3];
    const float* qp_b  = (const float*)d_in[4];
    const float* qp_s  = (const float*)d_in[5];
    const float* qp_o  = (const float*)d_in[6];
    const float* k_w   = (const float*)d_in[7];
    const float* k_b   = (const float*)d_in[8];
    const float* k_s   = (const float*)d_in[9];
    const float* k_o   = (const float*)d_in[10];
    const float* v_w   = (const float*)d_in[11];
    const float* v_b   = (const float*)d_in[12];
    const float* v_s   = (const float*)d_in[13];
    const float* v_o   = (const float*)d_in[14];
    const float* vl_w  = (const float*)d_in[15];
    const float* vl_b  = (const float*)d_in[16];
    const float* vl_s  = (const float*)d_in[17];
    const float* vl_o  = (const float*)d_in[18];
    const float* p_w   = (const float*)d_in[19];
    const float* p_b   = (const float*)d_in[20];
    const float* p_s   = (const float*)d_in[21];
    const float* p_o   = (const float*)d_in[22];
    const float* ab    = (const float*)d_in[23];
    const int*   bidx  = (const int*)d_in[24];
    float* out = (float*)d_out;

    int n_off = in_sizes[23] / HEADS;

    float* ws = (float*)d_ws;
    float* qin     = ws;                                   // 64*384*196
    float* qbuf    = qin    + (size_t)BATCH * DIMC * NN2;  // 64*128*196
    float* kbuf    = qbuf   + (size_t)BATCH * NH_KD * NN2; // 64*128*784
    float* vbuf    = kbuf   + (size_t)BATCH * NH_KD * NN;  // 64*512*784
    float* vlocal  = vbuf   + (size_t)BATCH * DH * NN;     // 64*512*196
    float* attnout = vlocal + (size_t)BATCH * DH * NN2;    // 64*512*196
    float* g       = kbuf;                                 // reuse k region

    // 1. qin
    qin_kernel<<<dim3(DIMC, BATCH), 256, 0, stream>>>(x, ql_w, ql_b, qin);
    // 2. q = bn(1x1(qin))   O=128, C=384, Nn=196
    conv1x1_mfma_kernel<<<dim3(4, NH_KD / 64, BATCH), 256, 0, stream>>>(qin, qp_w, qp_b, qp_s, qp_o, qbuf, DIMC, NN2);
    // 3. k = bn(1x1(x))     O=128, C=384, Nn=784
    conv1x1_mfma_kernel<<<dim3(13, NH_KD / 64, BATCH), 256, 0, stream>>>(x, k_w, k_b, k_s, k_o, kbuf, DIMC, NN);
    // 4. v = bn(1x1(x))     O=512, C=384, Nn=784
    conv1x1_mfma_kernel<<<dim3(13, DH / 64, BATCH), 256, 0, stream>>>(x, v_w, v_b, v_s, v_o, vbuf, DIMC, NN);
    // 5. v_local
    vlocal_kernel<<<dim3(DH, BATCH), 256, 0, stream>>>(vbuf, vl_w, vl_b, vl_s, vl_o, vlocal);
    // 6. attention
    attn_kernel<<<dim3(NN2, HEADS, BATCH), 256, 0, stream>>>(qbuf, kbuf, vbuf, ab, bidx, attnout, n_off);
    // 7. g = gelu(attnout + vlocal)
    {
        int total = BATCH * DH * NN2;
        gelu_add_kernel<<<(total + 255) / 256, 256, 0, stream>>>(attnout, vlocal, g, total);
    }
    // 8. out = bn(1x1(g))   O=384, C=512, Nn=196
    conv1x1_mfma_kernel<<<dim3(4, OUT_DIM / 64, BATCH), 256, 0, stream>>>(g, p_w, p_b, p_s, p_o, out, DH, NN2);
}

// Round 3
// 802.501 us; speedup vs baseline: 14.3276x; 3.4911x over previous
//
#include <hip/hip_runtime.h>
#include <math.h>

#define BATCH   64
#define DIMC    384
#define KEY_DIM 16
#define HEADS   8
#define DD      64      // per-head value dim
#define DH      512
#define NH_KD   128
#define RES     28
#define RES2    14
#define NN      784
#define NN2     196
#define OUT_DIM 384
#define SCALE   0.25f

typedef __attribute__((ext_vector_type(8))) short bf16x8;
typedef __attribute__((ext_vector_type(4))) float f32x4;

__device__ inline short f2bf(float f) {
    unsigned u = __float_as_uint(f);
    unsigned r = (u + 0x7fff + ((u >> 16) & 1)) >> 16;
    return (short)r;
}
__device__ inline float bf2f(short h) {
    return __uint_as_float(((unsigned)(unsigned short)h) << 16);
}

// ---------------- qin = dwconv3x3 stride2 (pad 1) + pool (x[::2,::2]) ----------------
__global__ void qin_kernel(const float* __restrict__ x, const float* __restrict__ ql_w,
                           const float* __restrict__ ql_b, float* __restrict__ qin) {
    int c = blockIdx.x;
    int b = blockIdx.y;
    int n2 = threadIdx.x;
    if (n2 >= NN2) return;
    int i = n2 / RES2, j = n2 % RES2;
    const float* xp = x + ((size_t)b * DIMC + c) * (RES * RES);
    const float* w  = ql_w + c * 9;
    float acc = ql_b[c];
    #pragma unroll
    for (int di = 0; di < 3; ++di) {
        int r = 2 * i + di - 1;
        if (r < 0 || r >= RES) continue;
        #pragma unroll
        for (int dj = 0; dj < 3; ++dj) {
            int cc = 2 * j + dj - 1;
            if (cc < 0 || cc >= RES) continue;
            acc += xp[r * RES + cc] * w[di * 3 + dj];
        }
    }
    acc += xp[(2 * i) * RES + 2 * j];
    qin[((size_t)b * DIMC + c) * NN2 + n2] = acc;
}

// ---------------- MFMA conv1x1 + bn  (split-bf16) ----------------
__global__ __launch_bounds__(256)
void conv1x1_mfma_kernel(const float* __restrict__ in, const float* __restrict__ w,
                         const float* __restrict__ bias, const float* __restrict__ s,
                         const float* __restrict__ off, float* __restrict__ out,
                         int C, int Nn) {
    __shared__ __align__(16) short Ahi[64][40];
    __shared__ __align__(16) short Alo[64][40];
    __shared__ __align__(16) short Bhi[64][40];
    __shared__ __align__(16) short Blo[64][40];

    const int t = threadIdx.x;
    const int n_base = blockIdx.x * 64;
    const int o_base = blockIdx.y * 64;
    const int b = blockIdx.z;
    const int O = gridDim.y * 64;
    const float* inb = in + (size_t)b * C * Nn;

    const int lane = t & 63;
    const int wid  = t >> 6;
    const int wm   = wid & 1;
    const int wn   = wid >> 1;
    const int lr   = lane & 15;
    const int kg   = lane >> 4;

    f32x4 acc[2][2];
    #pragma unroll
    for (int m = 0; m < 2; ++m)
        #pragma unroll
        for (int n = 0; n < 2; ++n)
            acc[m][n] = (f32x4){0.f, 0.f, 0.f, 0.f};

    const int a_c = t & 31, a_o = t >> 5;
    const int b_n = t & 63, b_c = t >> 6;
    const int gn = n_base + b_n;
    const bool nok = (gn < Nn);

    for (int k0 = 0; k0 < C; k0 += 32) {
        #pragma unroll
        for (int i = 0; i < 8; ++i) {
            int row = a_o + i * 8;
            float wv = w[(size_t)(o_base + row) * C + k0 + a_c];
            short h = f2bf(wv);
            Ahi[row][a_c] = h;
            Alo[row][a_c] = f2bf(wv - bf2f(h));
        }
        #pragma unroll
        for (int i = 0; i < 8; ++i) {
            int c = b_c + i * 4;
            float v = nok ? inb[(size_t)(k0 + c) * Nn + gn] : 0.f;
            short h = f2bf(v);
            Bhi[b_n][c] = h;
            Blo[b_n][c] = f2bf(v - bf2f(h));
        }
        __syncthreads();

        bf16x8 ah[2], al[2], bh[2], bl[2];
        #pragma unroll
        for (int m = 0; m < 2; ++m) {
            int row = wm * 32 + m * 16 + lr;
            ah[m] = *(const bf16x8*)&Ahi[row][kg * 8];
            al[m] = *(const bf16x8*)&Alo[row][kg * 8];
        }
        #pragma unroll
        for (int n = 0; n < 2; ++n) {
            int row = wn * 32 + n * 16 + lr;
            bh[n] = *(const bf16x8*)&Bhi[row][kg * 8];
            bl[n] = *(const bf16x8*)&Blo[row][kg * 8];
        }
        #pragma unroll
        for (int m = 0; m < 2; ++m)
            #pragma unroll
            for (int n = 0; n < 2; ++n) {
                acc[m][n] = __builtin_amdgcn_mfma_f32_16x16x32_bf16(ah[m], bh[n], acc[m][n], 0, 0, 0);
                acc[m][n] = __builtin_amdgcn_mfma_f32_16x16x32_bf16(ah[m], bl[n], acc[m][n], 0, 0, 0);
                acc[m][n] = __builtin_amdgcn_mfma_f32_16x16x32_bf16(al[m], bh[n], acc[m][n], 0, 0, 0);
            }
        __syncthreads();
    }

    #pragma unroll
    for (int m = 0; m < 2; ++m) {
        #pragma unroll
        for (int n = 0; n < 2; ++n) {
            int col = n_base + wn * 32 + n * 16 + lr;
            if (col >= Nn) continue;
            #pragma unroll
            for (int r = 0; r < 4; ++r) {
                int row = o_base + wm * 32 + m * 16 + kg * 4 + r;
                float a = s[row];
                float v = acc[m][n][r] * a + (bias[row] * a + off[row]);
                out[((size_t)b * O + row) * Nn + col] = v;
            }
        }
    }
}

// ---------------- v_local ----------------
__global__ void vlocal_kernel(const float* __restrict__ v, const float* __restrict__ vl_w,
                              const float* __restrict__ vl_b, const float* __restrict__ vl_s,
                              const float* __restrict__ vl_o, float* __restrict__ vlocal) {
    int c = blockIdx.x;
    int b = blockIdx.y;
    int n2 = threadIdx.x;
    if (n2 >= NN2) return;
    int i = n2 / RES2, j = n2 % RES2;
    const float* vp = v + ((size_t)b * DH + c) * NN;
    const float* w  = vl_w + c * 9;
    float acc = vl_b[c];
    #pragma unroll
    for (int di = 0; di < 3; ++di) {
        int r = 2 * i + di - 1;
        if (r < 0 || r >= RES) continue;
        #pragma unroll
        for (int dj = 0; dj < 3; ++dj) {
            int cc = 2 * j + dj - 1;
            if (cc < 0 || cc >= RES) continue;
            acc += vp[r * RES + cc] * w[di * 3 + dj];
        }
    }
    vlocal[((size_t)b * DH + c) * NN2 + n2] = acc * vl_s[c] + vl_o[c];
}

// ---------------- bias expand: biasM[h][q][key] = ab[h][bidx[q*784+key]] ----------------
__global__ void bias_expand_kernel(const float* __restrict__ ab, const int* __restrict__ bidx,
                                   float* __restrict__ biasM, int n_off) {
    int i = blockIdx.x * 256 + threadIdx.x;
    int h = blockIdx.y;
    if (i >= NN2 * NN) return;
    biasM[(size_t)h * NN2 * NN + i] = ab[h * n_off + bidx[i]];
}

// ---------------- MFMA attention: block = (qtile of 64, h, b), 4 waves ----------------
__global__ __launch_bounds__(256)
void attn_mfma_kernel(const float* __restrict__ q, const float* __restrict__ k,
                      const float* __restrict__ v, const float* __restrict__ biasM,
                      float* __restrict__ attnout) {
    __shared__ __align__(16) short Qhi[64][40], Qlo[64][40];   // [q_local][c]
    __shared__ __align__(16) short Khi[64][40], Klo[64][40];   // [key_local][c]
    __shared__ __align__(16) short Vhi[64][72], Vlo[64][72];   // [d][key_local]
    __shared__ __align__(16) short Ps[4][16][72];              // [wave][q16][key_local]

    const int t = threadIdx.x;
    const int qt = blockIdx.x;     // 0..3
    const int h  = blockIdx.y;
    const int b  = blockIdx.z;
    const int lane = t & 63;
    const int wid  = t >> 6;
    const int lr = lane & 15;
    const int kg = lane >> 4;

    // zero Q/K arrays (zero-padded c columns 16..31 must stay 0)
    {
        int* z;
        z = (int*)&Qhi[0][0]; for (int i = t; i < 1280; i += 256) z[i] = 0;
        z = (int*)&Qlo[0][0]; for (int i = t; i < 1280; i += 256) z[i] = 0;
        z = (int*)&Khi[0][0]; for (int i = t; i < 1280; i += 256) z[i] = 0;
        z = (int*)&Klo[0][0]; for (int i = t; i < 1280; i += 256) z[i] = 0;
    }
    __syncthreads();

    // stage Q: [64 q][16 c]; float4 over q
    {
        int c = t >> 4;
        int q4 = (t & 15) * 4;
        int col = qt * 64 + q4;
        float4 qv = {0.f, 0.f, 0.f, 0.f};
        if (col + 4 <= NN2)
            qv = *(const float4*)&q[((size_t)(b * NH_KD + h * KEY_DIM + c)) * NN2 + col];
        #pragma unroll
        for (int j = 0; j < 4; ++j) {
            float val = (&qv.x)[j];
            short hh = f2bf(val);
            Qhi[q4 + j][c] = hh;
            Qlo[q4 + j][c] = f2bf(val - bf2f(hh));
        }
    }

    const float* kbase = k + ((size_t)(b * NH_KD + h * KEY_DIM)) * NN;
    const float* vbase = v + ((size_t)(b * DH + h * DD)) * NN;

    f32x4 acc_o[4];
    float sacc[4];
    #pragma unroll
    for (int n = 0; n < 4; ++n) acc_o[n] = (f32x4){0.f, 0.f, 0.f, 0.f};
    #pragma unroll
    for (int r = 0; r < 4; ++r) sacc[r] = 0.f;

    bf16x8 qa_h, qa_l;

    for (int tile = 0; tile < 13; ++tile) {
        const int k0 = tile * 64;
        __syncthreads();   // prev PV done before restaging K/V

        // stage K: [64 key][16 c]
        {
            int c = t >> 4;
            int key4 = (t & 15) * 4;
            float4 kv = {0.f, 0.f, 0.f, 0.f};
            if (k0 + key4 + 4 <= NN)
                kv = *(const float4*)&kbase[(size_t)c * NN + k0 + key4];
            #pragma unroll
            for (int j = 0; j < 4; ++j) {
                float val = (&kv.x)[j];
                short hh = f2bf(val);
                Khi[key4 + j][c] = hh;
                Klo[key4 + j][c] = f2bf(val - bf2f(hh));
            }
        }
        // stage V: [64 d][64 key]
        {
            int key4 = (t & 15) * 4;
            bool ok = (k0 + key4 + 4 <= NN);
            #pragma unroll
            for (int i = 0; i < 4; ++i) {
                int d = (t >> 4) + i * 16;
                float4 vv = {0.f, 0.f, 0.f, 0.f};
                if (ok) vv = *(const float4*)&vbase[(size_t)d * NN + k0 + key4];
                #pragma unroll
                for (int j = 0; j < 4; ++j) {
                    float val = (&vv.x)[j];
                    short hh = f2bf(val);
                    Vhi[d][key4 + j] = hh;
                    Vlo[d][key4 + j] = f2bf(val - bf2f(hh));
                }
            }
        }
        __syncthreads();

        if (tile == 0) {
            qa_h = *(const bf16x8*)&Qhi[wid * 16 + lr][kg * 8];
            qa_l = *(const bf16x8*)&Qlo[wid * 16 + lr][kg * 8];
        }

        // QK^T + bias + exp + store P
        #pragma unroll
        for (int nt = 0; nt < 4; ++nt) {
            bf16x8 kb_h = *(const bf16x8*)&Khi[nt * 16 + lr][kg * 8];
            bf16x8 kb_l = *(const bf16x8*)&Klo[nt * 16 + lr][kg * 8];
            f32x4 s = (f32x4){0.f, 0.f, 0.f, 0.f};
            s = __builtin_amdgcn_mfma_f32_16x16x32_bf16(qa_h, kb_h, s, 0, 0, 0);
            s = __builtin_amdgcn_mfma_f32_16x16x32_bf16(qa_h, kb_l, s, 0, 0, 0);
            s = __builtin_amdgcn_mfma_f32_16x16x32_bf16(qa_l, kb_h, s, 0, 0, 0);

            int key = k0 + nt * 16 + lr;
            bool kval = (key < NN);
            int qrow0 = qt * 64 + wid * 16 + kg * 4;
            const float* bp = biasM + ((size_t)h * NN2 + qrow0) * NN + key;
            #pragma unroll
            for (int r = 0; r < 4; ++r) {
                float bias = (kval && (qrow0 + r) < NN2) ? bp[(size_t)r * NN] : 0.f;
                float sv = s[r] * SCALE + bias;
                float pv = kval ? __expf(sv) : 0.f;
                sacc[r] += pv;
                Ps[wid][kg * 4 + r][nt * 16 + lr] = f2bf(pv);
            }
        }

        // PV (Ps is wave-private; LDS dependency handled by compiler waitcnt)
        #pragma unroll
        for (int ks = 0; ks < 2; ++ks) {
            bf16x8 pa = *(const bf16x8*)&Ps[wid][lr][ks * 32 + kg * 8];
            #pragma unroll
            for (int nt = 0; nt < 4; ++nt) {
                bf16x8 vh = *(const bf16x8*)&Vhi[nt * 16 + lr][ks * 32 + kg * 8];
                bf16x8 vl = *(const bf16x8*)&Vlo[nt * 16 + lr][ks * 32 + kg * 8];
                acc_o[nt] = __builtin_amdgcn_mfma_f32_16x16x32_bf16(pa, vh, acc_o[nt], 0, 0, 0);
                acc_o[nt] = __builtin_amdgcn_mfma_f32_16x16x32_bf16(pa, vl, acc_o[nt], 0, 0, 0);
            }
        }
    }

    // reduce row sums across the 16 lanes of each kg-group
    #pragma unroll
    for (int m = 1; m < 16; m <<= 1) {
        #pragma unroll
        for (int r = 0; r < 4; ++r)
            sacc[r] += __shfl_xor(sacc[r], m, 64);
    }

    #pragma unroll
    for (int r = 0; r < 4; ++r) {
        int qrow = qt * 64 + wid * 16 + kg * 4 + r;
        if (qrow >= NN2) continue;
        float inv = 1.f / sacc[r];
        #pragma unroll
        for (int nt = 0; nt < 4; ++nt) {
            int d = nt * 16 + lr;
            attnout[((size_t)(b * DH + h * DD + d)) * NN2 + qrow] = acc_o[nt][r] * inv;
        }
    }
}

// ---------------- g = gelu(attnout + vlocal) ----------------
__global__ void gelu_add_kernel(const float* __restrict__ a, const float* __restrict__ vl,
                                float* __restrict__ g, int total) {
    int i = blockIdx.x * blockDim.x + threadIdx.x;
    if (i >= total) return;
    float x = a[i] + vl[i];
    g[i] = 0.5f * x * (1.f + erff(x * 0.70710678118654752440f));
}

extern "C" void kernel_launch(void* const* d_in, const int* in_sizes, int n_in,
                              void* d_out, int out_size, void* d_ws, size_t ws_size,
                              hipStream_t stream) {
    const float* x     = (const float*)d_in[0];
    const float* ql_w  = (const float*)d_in[1];
    const float* ql_b  = (const float*)d_in[2];
    const float* qp_w  = (const float*)d_in[3];
    const float* qp_b  = (const float*)d_in[4];
    const float* qp_s  = (const float*)d_in[5];
    const float* qp_o  = (const float*)d_in[6];
    const float* k_w   = (const float*)d_in[7];
    const float* k_b   = (const float*)d_in[8];
    const float* k_s   = (const float*)d_in[9];
    const float* k_o   = (const float*)d_in[10];
    const float* v_w   = (const float*)d_in[11];
    const float* v_b   = (const float*)d_in[12];
    const float* v_s   = (const float*)d_in[13];
    const float* v_o   = (const float*)d_in[14];
    const float* vl_w  = (const float*)d_in[15];
    const float* vl_b  = (const float*)d_in[16];
    const float* vl_s  = (const float*)d_in[17];
    const float* vl_o  = (const float*)d_in[18];
    const float* p_w   = (const float*)d_in[19];
    const float* p_b   = (const float*)d_in[20];
    const float* p_s   = (const float*)d_in[21];
    const float* p_o   = (const float*)d_in[22];
    const float* ab    = (const float*)d_in[23];
    const int*   bidx  = (const int*)d_in[24];
    float* out = (float*)d_out;

    int n_off = in_sizes[23] / HEADS;

    float* ws = (float*)d_ws;
    float* qin     = ws;                                   // 64*384*196 (later reused as biasM)
    float* qbuf    = qin    + (size_t)BATCH * DIMC * NN2;
    float* kbuf    = qbuf   + (size_t)BATCH * NH_KD * NN2;
    float* vbuf    = kbuf   + (size_t)BATCH * NH_KD * NN;
    float* vlocal  = vbuf   + (size_t)BATCH * DH * NN;
    float* attnout = vlocal + (size_t)BATCH * DH * NN2;
    float* g       = kbuf;                                 // reuse k region after attn
    float* biasM   = qin;                                  // reuse qin region after q proj (needs 8*196*784)

    // 1. qin
    qin_kernel<<<dim3(DIMC, BATCH), 256, 0, stream>>>(x, ql_w, ql_b, qin);
    // 2. q = bn(1x1(qin))
    conv1x1_mfma_kernel<<<dim3(4, NH_KD / 64, BATCH), 256, 0, stream>>>(qin, qp_w, qp_b, qp_s, qp_o, qbuf, DIMC, NN2);
    // 2b. expand bias into (dead) qin region
    bias_expand_kernel<<<dim3((NN2 * NN + 255) / 256, HEADS), 256, 0, stream>>>(ab, bidx, biasM, n_off);
    // 3. k = bn(1x1(x))
    conv1x1_mfma_kernel<<<dim3(13, NH_KD / 64, BATCH), 256, 0, stream>>>(x, k_w, k_b, k_s, k_o, kbuf, DIMC, NN);
    // 4. v = bn(1x1(x))
    conv1x1_mfma_kernel<<<dim3(13, DH / 64, BATCH), 256, 0, stream>>>(x, v_w, v_b, v_s, v_o, vbuf, DIMC, NN);
    // 5. v_local
    vlocal_kernel<<<dim3(DH, BATCH), 256, 0, stream>>>(vbuf, vl_w, vl_b, vl_s, vl_o, vlocal);
    // 6. attention (MFMA)
    attn_mfma_kernel<<<dim3(4, HEADS, BATCH), 256, 0, stream>>>(qbuf, kbuf, vbuf, biasM, attnout);
    // 7. g = gelu(attnout + vlocal)
    {
        int total = BATCH * DH * NN2;
        gelu_add_kernel<<<(total + 255) / 256, 256, 0, stream>>>(attnout, vlocal, g, total);
    }
    // 8. out = bn(1x1(g))
    conv1x1_mfma_kernel<<<dim3(4, OUT_DIM / 64, BATCH), 256, 0, stream>>>(g, p_w, p_b, p_s, p_o, out, DH, NN2);
}

// Round 4
// 570.023 us; speedup vs baseline: 20.1710x; 1.4078x over previous
//
#include <hip/hip_runtime.h>
#include <math.h>

#define BATCH   64
#define DIMC    384
#define KEY_DIM 16
#define HEADS   8
#define DD      64
#define DH      512
#define NH_KD   128
#define RES     28
#define RES2    14
#define NN      784
#define NN2     196
#define OUT_DIM 384
#define SCALE   0.25f
#define XPAD    896     // 7*128
#define QPAD    256     // 2*128

typedef __attribute__((ext_vector_type(8))) short bf16x8;
typedef __attribute__((ext_vector_type(4))) float f32x4;

#define MFMA32(a, b, c) __builtin_amdgcn_mfma_f32_16x16x32_bf16(a, b, c, 0, 0, 0)

__device__ inline short f2bf(float f) {
    unsigned u = __float_as_uint(f);
    unsigned r = (u + 0x7fff + ((u >> 16) & 1)) >> 16;
    return (short)r;
}
__device__ inline float bf2f(short h) {
    return __uint_as_float(((unsigned)(unsigned short)h) << 16);
}

// ws byte offsets (total 229,836,800 B)
#define O_QIN      0u
#define O_QINT_HI  20971520u
#define O_QINT_LO  33554432u
#define O_XT_HI    0u
#define O_XT_LO    44040192u
#define O_VLOCAL   0u
#define O_ATTNT    25690112u
#define O_GT_HI    51380224u
#define O_GT_LO    68157440u
#define O_Q_HI     88080384u
#define O_Q_LO     91291648u
#define O_K_HI     94502912u
#define O_K_LO     107347968u
#define O_V_HI     120193024u
#define O_V_LO     171573248u
#define O_BIASM    222953472u
#define O_W_HI     227870720u
#define O_W_LO     228853760u
// weight element offsets inside w_hi/w_lo: qp@0, k@49152, v@98304, p@294912

// ---------------- qin = dwconv3x3 s2 (pad 1) + pool ----------------
__global__ void qin_kernel(const float* __restrict__ x, const float* __restrict__ ql_w,
                           const float* __restrict__ ql_b, float* __restrict__ qin) {
    int c = blockIdx.x, b = blockIdx.y, n2 = threadIdx.x;
    if (n2 >= NN2) return;
    int i = n2 / RES2, j = n2 % RES2;
    const float* xp = x + ((size_t)b * DIMC + c) * (RES * RES);
    const float* w  = ql_w + c * 9;
    float acc = ql_b[c];
    #pragma unroll
    for (int di = 0; di < 3; ++di) {
        int r = 2 * i + di - 1;
        if (r < 0 || r >= RES) continue;
        #pragma unroll
        for (int dj = 0; dj < 3; ++dj) {
            int cc = 2 * j + dj - 1;
            if (cc < 0 || cc >= RES) continue;
            acc += xp[r * RES + cc] * w[di * 3 + dj];
        }
    }
    acc += xp[(2 * i) * RES + 2 * j];
    qin[((size_t)b * DIMC + c) * NN2 + n2] = acc;
}

// ---------------- weight split (4 tensors concatenated) ----------------
__global__ void wsplit_kernel(const float* __restrict__ w0, const float* __restrict__ w1,
                              const float* __restrict__ w2, const float* __restrict__ w3,
                              short* __restrict__ hi, short* __restrict__ lo) {
    int i = blockIdx.x * 256 + threadIdx.x;
    if (i >= 491520) return;
    const float* src; int j = i;
    if (j < 49152) src = w0;
    else if (j < 98304) { src = w1; j -= 49152; }
    else if (j < 294912) { src = w2; j -= 98304; }
    else { src = w3; j -= 294912; }
    float v = src[j];
    short h = f2bf(v);
    hi[i] = h;
    lo[i] = f2bf(v - bf2f(h));
}

// ---------------- transpose + split: [b][C][N] f32 -> [b][Npad][C] bf16 hi/lo ----------------
__global__ void tsplit_kernel(const float* __restrict__ in, short* __restrict__ out_hi,
                              short* __restrict__ out_lo, int C, int N, int Npad) {
    __shared__ float tile[32][33];
    int ntb = blockIdx.x * 32, ctb = blockIdx.y * 32, b = blockIdx.z;
    int tn = threadIdx.x & 31, tc4 = threadIdx.x >> 5;
    #pragma unroll
    for (int i = 0; i < 4; ++i) {
        int c = tc4 + i * 8;
        int n = ntb + tn;
        tile[c][tn] = (n < N) ? in[((size_t)b * C + ctb + c) * N + n] : 0.f;
    }
    __syncthreads();
    int tc = threadIdx.x & 31, tn4 = threadIdx.x >> 5;
    #pragma unroll
    for (int i = 0; i < 4; ++i) {
        int n = tn4 + i * 8;
        float v = tile[tc][n];
        short h = f2bf(v);
        size_t o = ((size_t)b * Npad + ntb + n) * C + ctb + tc;
        out_hi[o] = h;
        out_lo[o] = f2bf(v - bf2f(h));
    }
}

// ---------------- split-bf16 MFMA GEMM: out[b,o,n] = bn(sum_c w[o,c] * in[b,n,c]) ----------------
// A = weights [O][C] hi/lo, B = activations [b][Npad][C] hi/lo
// 128x128 tile, BK=32, 4 waves (2x2), wave = 64x64 (4x4 frags)
__global__ __launch_bounds__(256)
void gemm_split_kernel(const short* __restrict__ Ag_hi, const short* __restrict__ Ag_lo,
                       const short* __restrict__ Bg_hi, const short* __restrict__ Bg_lo,
                       const float* __restrict__ bias, const float* __restrict__ s,
                       const float* __restrict__ off,
                       float* __restrict__ out_f, short* __restrict__ out_hi,
                       short* __restrict__ out_lo, int mode,
                       int C, int Nn, int Npad) {
    __shared__ __align__(16) short Ah[128 * 32], Al[128 * 32], Bh[128 * 32], Bl[128 * 32];

    const int t = threadIdx.x;
    const int n0 = blockIdx.x * 128, o0 = blockIdx.y * 128, b = blockIdx.z;
    const int O = gridDim.y * 128;
    const int lane = t & 63, wid = t >> 6;
    const int wm = wid & 1, wn = wid >> 1;
    const int lr = lane & 15, kg = lane >> 4;

    f32x4 acc[4][4];
    #pragma unroll
    for (int m = 0; m < 4; ++m)
        #pragma unroll
        for (int n = 0; n < 4; ++n)
            acc[m][n] = (f32x4){0.f, 0.f, 0.f, 0.f};

    const int srow = t >> 2;
    const int sch  = (t & 3) * 8;
    const size_t aBase = (size_t)(o0 + srow) * C + sch;
    const size_t bBase = ((size_t)b * Npad + n0 + srow) * C + sch;
    const size_t rstep = (size_t)64 * C;

    bf16x8 rA[2], rAl[2], rB[2], rBl[2];
    #pragma unroll
    for (int p = 0; p < 2; ++p) {
        rA[p]  = *(const bf16x8*)(Ag_hi + aBase + p * rstep);
        rAl[p] = *(const bf16x8*)(Ag_lo + aBase + p * rstep);
        rB[p]  = *(const bf16x8*)(Bg_hi + bBase + p * rstep);
        rBl[p] = *(const bf16x8*)(Bg_lo + bBase + p * rstep);
    }

    for (int k0 = 0;; k0 += 32) {
        #pragma unroll
        for (int p = 0; p < 2; ++p) {
            int la = (srow + p * 64) * 32 + sch;
            *(bf16x8*)&Ah[la] = rA[p];
            *(bf16x8*)&Al[la] = rAl[p];
            *(bf16x8*)&Bh[la] = rB[p];
            *(bf16x8*)&Bl[la] = rBl[p];
        }
        __syncthreads();

        if (k0 + 32 < C) {
            #pragma unroll
            for (int p = 0; p < 2; ++p) {
                rA[p]  = *(const bf16x8*)(Ag_hi + aBase + (k0 + 32) + p * rstep);
                rAl[p] = *(const bf16x8*)(Ag_lo + aBase + (k0 + 32) + p * rstep);
                rB[p]  = *(const bf16x8*)(Bg_hi + bBase + (k0 + 32) + p * rstep);
                rBl[p] = *(const bf16x8*)(Bg_lo + bBase + (k0 + 32) + p * rstep);
            }
        }

        bf16x8 ah[4], al[4];
        #pragma unroll
        for (int m = 0; m < 4; ++m) {
            int row = wm * 64 + m * 16 + lr;
            ah[m] = *(const bf16x8*)&Ah[row * 32 + kg * 8];
            al[m] = *(const bf16x8*)&Al[row * 32 + kg * 8];
        }
        #pragma unroll
        for (int nf = 0; nf < 4; ++nf) {
            int row = wn * 64 + nf * 16 + lr;
            bf16x8 bh = *(const bf16x8*)&Bh[row * 32 + kg * 8];
            bf16x8 bl = *(const bf16x8*)&Bl[row * 32 + kg * 8];
            #pragma unroll
            for (int m = 0; m < 4; ++m) {
                acc[m][nf] = MFMA32(ah[m], bh, acc[m][nf]);
                acc[m][nf] = MFMA32(ah[m], bl, acc[m][nf]);
                acc[m][nf] = MFMA32(al[m], bh, acc[m][nf]);
            }
        }
        if (k0 + 32 >= C) break;
        __syncthreads();
    }

    // epilogue + bn
    #pragma unroll
    for (int m = 0; m < 4; ++m) {
        #pragma unroll
        for (int nf = 0; nf < 4; ++nf) {
            int col = n0 + wn * 64 + nf * 16 + lr;
            if (col >= Nn) continue;
            #pragma unroll
            for (int r = 0; r < 4; ++r) {
                int row = o0 + wm * 64 + m * 16 + kg * 4 + r;
                float a = s[row];
                float v = acc[m][nf][r] * a + (bias[row] * a + off[row]);
                size_t oidx = ((size_t)b * O + row) * Nn + col;
                if (mode == 0) {
                    out_f[oidx] = v;
                } else {
                    short h = f2bf(v);
                    out_hi[oidx] = h;
                    out_lo[oidx] = f2bf(v - bf2f(h));
                }
            }
        }
    }
}

// ---------------- v_local = bn(dwconv3x3 s2 over v) ; v given as hi/lo ----------------
__global__ void vlocal_kernel(const short* __restrict__ vh, const short* __restrict__ vl,
                              const float* __restrict__ vl_w, const float* __restrict__ vl_b,
                              const float* __restrict__ vl_s, const float* __restrict__ vl_o,
                              float* __restrict__ vlocal) {
    int c = blockIdx.x, b = blockIdx.y, n2 = threadIdx.x;
    if (n2 >= NN2) return;
    int i = n2 / RES2, j = n2 % RES2;
    const size_t base = ((size_t)b * DH + c) * NN;
    const float* w = vl_w + c * 9;
    float acc = vl_b[c];
    #pragma unroll
    for (int di = 0; di < 3; ++di) {
        int r = 2 * i + di - 1;
        if (r < 0 || r >= RES) continue;
        #pragma unroll
        for (int dj = 0; dj < 3; ++dj) {
            int cc = 2 * j + dj - 1;
            if (cc < 0 || cc >= RES) continue;
            size_t idx = base + r * RES + cc;
            acc += (bf2f(vh[idx]) + bf2f(vl[idx])) * w[di * 3 + dj];
        }
    }
    vlocal[((size_t)b * DH + c) * NN2 + n2] = acc * vl_s[c] + vl_o[c];
}

// ---------------- bias expand ----------------
__global__ void bias_expand_kernel(const float* __restrict__ ab, const int* __restrict__ bidx,
                                   float* __restrict__ biasM, int n_off) {
    int i = blockIdx.x * 256 + threadIdx.x;
    int h = blockIdx.y;
    if (i >= NN2 * NN) return;
    biasM[(size_t)h * NN2 * NN + i] = ab[h * n_off + bidx[i]];
}

// ---------------- MFMA attention (swapped QK^T), out transposed [b][q][dh] ----------------
__global__ __launch_bounds__(256)
void attn_mfma2_kernel(const short* __restrict__ qh, const short* __restrict__ ql,
                       const short* __restrict__ kh, const short* __restrict__ kl,
                       const short* __restrict__ vh, const short* __restrict__ vl,
                       const float* __restrict__ biasM, float* __restrict__ outT) {
    __shared__ __align__(16) short Qh[64][32], Ql[64][32], Kh[64][32], Kl[64][32];
    __shared__ __align__(16) short Vh[64][64], Vl[64][64];
    __shared__ __align__(16) short Ps[4][16 * 64];   // [wave][q16][key64], XOR-swizzled

    const int t = threadIdx.x;
    const int qt = blockIdx.x, h = blockIdx.y, b = blockIdx.z;
    const int lane = t & 63, wid = t >> 6;
    const int lr = lane & 15, kg = lane >> 4;

    {   // zero Q/K tiles (c cols 16..31 must stay 0)
        int* z;
        z = (int*)&Qh[0][0]; for (int i = t; i < 1024; i += 256) z[i] = 0;
        z = (int*)&Ql[0][0]; for (int i = t; i < 1024; i += 256) z[i] = 0;
        z = (int*)&Kh[0][0]; for (int i = t; i < 1024; i += 256) z[i] = 0;
        z = (int*)&Kl[0][0]; for (int i = t; i < 1024; i += 256) z[i] = 0;
    }
    __syncthreads();

    {   // stage Q [64 q][16 c]
        int c = t >> 4, q4 = (t & 15) * 4;
        size_t base = ((size_t)(b * NH_KD + h * KEY_DIM + c)) * NN2 + qt * 64 + q4;
        short4 hv = {0, 0, 0, 0}, lv = {0, 0, 0, 0};
        if (qt * 64 + q4 + 3 < NN2) {
            hv = *(const short4*)(qh + base);
            lv = *(const short4*)(ql + base);
        }
        #pragma unroll
        for (int j = 0; j < 4; ++j) {
            Qh[q4 + j][c] = ((const short*)&hv)[j];
            Ql[q4 + j][c] = ((const short*)&lv)[j];
        }
    }

    f32x4 acc[4];
    #pragma unroll
    for (int n = 0; n < 4; ++n) acc[n] = (f32x4){0.f, 0.f, 0.f, 0.f};
    float sacc = 0.f;
    bf16x8 qa_h, qa_l;
    char* Psw = (char*)&Ps[wid][0];
    const int qg = qt * 64 + wid * 16 + lr;

    for (int tile = 0; tile < 13; ++tile) {
        const int k0 = tile * 64;
        __syncthreads();

        {   // stage K [64 key][16 c]
            int c = t >> 4, key4 = (t & 15) * 4;
            size_t base = ((size_t)(b * NH_KD + h * KEY_DIM + c)) * NN + k0 + key4;
            short4 hv = {0, 0, 0, 0}, lv = {0, 0, 0, 0};
            if (k0 + key4 + 3 < NN) {
                hv = *(const short4*)(kh + base);
                lv = *(const short4*)(kl + base);
            }
            #pragma unroll
            for (int j = 0; j < 4; ++j) {
                Kh[key4 + j][c] = ((const short*)&hv)[j];
                Kl[key4 + j][c] = ((const short*)&lv)[j];
            }
        }
        {   // stage V [64 d][64 key]
            int key4 = (t & 15) * 4;
            bool ok = (k0 + key4 + 3) < NN;
            #pragma unroll
            for (int i = 0; i < 4; ++i) {
                int d = (t >> 4) + i * 16;
                size_t base = ((size_t)(b * DH + h * DD + d)) * NN + k0 + key4;
                short4 hv = {0, 0, 0, 0}, lv = {0, 0, 0, 0};
                if (ok) {
                    hv = *(const short4*)(vh + base);
                    lv = *(const short4*)(vl + base);
                }
                *(short4*)&Vh[d][key4] = hv;
                *(short4*)&Vl[d][key4] = lv;
            }
        }
        __syncthreads();

        if (tile == 0) {
            qa_h = *(const bf16x8*)&Qh[wid * 16 + lr][kg * 8];
            qa_l = *(const bf16x8*)&Ql[wid * 16 + lr][kg * 8];
        }

        // QK^T swapped: A=K rows(keys), B=Q cols(q). D: col=lr=q, row=kg*4+r=key
        #pragma unroll
        for (int nt = 0; nt < 4; ++nt) {
            bf16x8 ka_h = *(const bf16x8*)&Kh[nt * 16 + lr][kg * 8];
            bf16x8 ka_l = *(const bf16x8*)&Kl[nt * 16 + lr][kg * 8];
            f32x4 sc = (f32x4){0.f, 0.f, 0.f, 0.f};
            sc = MFMA32(ka_h, qa_h, sc);
            sc = MFMA32(ka_h, qa_l, sc);
            sc = MFMA32(ka_l, qa_h, sc);

            int keyb = k0 + nt * 16 + kg * 4;
            bool kvalid = (keyb + 3) < NN;
            float4 bias4 = {0.f, 0.f, 0.f, 0.f};
            if (kvalid && qg < NN2)
                bias4 = *(const float4*)&biasM[((size_t)h * NN2 + qg) * NN + keyb];
            short4 pk;
            #pragma unroll
            for (int r = 0; r < 4; ++r) {
                float sv = sc[r] * SCALE + ((const float*)&bias4)[r];
                float pv = kvalid ? __expf(sv) : 0.f;
                sacc += pv;
                ((short*)&pk)[r] = f2bf(pv);
            }
            *(short4*)(Psw + lr * 128 + ((nt * 32 + kg * 8) ^ ((lr & 7) << 4))) = pk;
        }

        // PV: A=P rows(q), B=V cols(d). acc[nt]: d = nt*16+lr, q = kg*4+r
        #pragma unroll
        for (int ks = 0; ks < 2; ++ks) {
            bf16x8 pa = *(const bf16x8*)(Psw + lr * 128 + ((ks * 64 + kg * 16) ^ ((lr & 7) << 4)));
            #pragma unroll
            for (int nt = 0; nt < 4; ++nt) {
                bf16x8 vfh = *(const bf16x8*)&Vh[nt * 16 + lr][ks * 32 + kg * 8];
                bf16x8 vfl = *(const bf16x8*)&Vl[nt * 16 + lr][ks * 32 + kg * 8];
                acc[nt] = MFMA32(pa, vfh, acc[nt]);
                acc[nt] = MFMA32(pa, vfl, acc[nt]);
            }
        }
    }

    // row-sum reduce across kg groups (same q lives in lanes lr, lr+16, lr+32, lr+48)
    sacc += __shfl_xor(sacc, 16, 64);
    sacc += __shfl_xor(sacc, 32, 64);

    #pragma unroll
    for (int r = 0; r < 4; ++r) {
        int qrow = qt * 64 + wid * 16 + kg * 4 + r;
        if (qrow >= NN2) continue;
        float inv = 1.f / __shfl(sacc, kg * 4 + r, 64);
        #pragma unroll
        for (int nt = 0; nt < 4; ++nt) {
            int d = nt * 16 + lr;
            outT[((size_t)b * NN2 + qrow) * DH + h * DD + d] = acc[nt][r] * inv;
        }
    }
}

// ---------------- gelu(attnT + vlocal^T) -> gT hi/lo [b][QPAD][512] ----------------
__global__ void gelu_addT_kernel(const float* __restrict__ aT, const float* __restrict__ vloc,
                                 short* __restrict__ g_hi, short* __restrict__ g_lo) {
    __shared__ float tile[32][33];
    int ntb = blockIdx.x * 32, ctb = blockIdx.y * 32, b = blockIdx.z;
    int tn = threadIdx.x & 31, tc4 = threadIdx.x >> 5;
    #pragma unroll
    for (int i = 0; i < 4; ++i) {
        int c = tc4 + i * 8;
        int n = ntb + tn;
        tile[c][tn] = (n < NN2) ? vloc[((size_t)b * DH + ctb + c) * NN2 + n] : 0.f;
    }
    __syncthreads();
    int tc = threadIdx.x & 31, tn4 = threadIdx.x >> 5;
    #pragma unroll
    for (int i = 0; i < 4; ++i) {
        int n = ntb + tn4 + i * 8;
        float g = 0.f;
        if (n < NN2) {
            float sum = aT[((size_t)b * NN2 + n) * DH + ctb + tc] + tile[tc][tn4 + i * 8];
            g = 0.5f * sum * (1.f + erff(sum * 0.70710678118654752440f));
        }
        short hh = f2bf(g);
        size_t o = ((size_t)b * QPAD + n) * DH + ctb + tc;
        g_hi[o] = hh;
        g_lo[o] = f2bf(g - bf2f(hh));
    }
}

extern "C" void kernel_launch(void* const* d_in, const int* in_sizes, int n_in,
                              void* d_out, int out_size, void* d_ws, size_t ws_size,
                              hipStream_t stream) {
    const float* x     = (const float*)d_in[0];
    const float* ql_w  = (const float*)d_in[1];
    const float* ql_b  = (const float*)d_in[2];
    const float* qp_w  = (const float*)d_in[3];
    const float* qp_b  = (const float*)d_in[4];
    const float* qp_s  = (const float*)d_in[5];
    const float* qp_o  = (const float*)d_in[6];
    const float* k_w   = (const float*)d_in[7];
    const float* k_b   = (const float*)d_in[8];
    const float* k_s   = (const float*)d_in[9];
    const float* k_o   = (const float*)d_in[10];
    const float* v_w   = (const float*)d_in[11];
    const float* v_b   = (const float*)d_in[12];
    const float* v_s   = (const float*)d_in[13];
    const float* v_o   = (const float*)d_in[14];
    const float* vl_w  = (const float*)d_in[15];
    const float* vl_b  = (const float*)d_in[16];
    const float* vl_s  = (const float*)d_in[17];
    const float* vl_o  = (const float*)d_in[18];
    const float* p_w   = (const float*)d_in[19];
    const float* p_b   = (const float*)d_in[20];
    const float* p_s   = (const float*)d_in[21];
    const float* p_o   = (const float*)d_in[22];
    const float* ab    = (const float*)d_in[23];
    const int*   bidx  = (const int*)d_in[24];
    float* out = (float*)d_out;
    int n_off = in_sizes[23] / HEADS;

    char* ws = (char*)d_ws;
    float* qin    = (float*)(ws + O_QIN);
    short* qinT_h = (short*)(ws + O_QINT_HI);
    short* qinT_l = (short*)(ws + O_QINT_LO);
    short* xT_h   = (short*)(ws + O_XT_HI);
    short* xT_l   = (short*)(ws + O_XT_LO);
    float* vlocal = (float*)(ws + O_VLOCAL);
    float* attnT  = (float*)(ws + O_ATTNT);
    short* gT_h   = (short*)(ws + O_GT_HI);
    short* gT_l   = (short*)(ws + O_GT_LO);
    short* q_h    = (short*)(ws + O_Q_HI);
    short* q_l    = (short*)(ws + O_Q_LO);
    short* k_h    = (short*)(ws + O_K_HI);
    short* k_l    = (short*)(ws + O_K_LO);
    short* v_h    = (short*)(ws + O_V_HI);
    short* v_l    = (short*)(ws + O_V_LO);
    float* biasM  = (float*)(ws + O_BIASM);
    short* w_h    = (short*)(ws + O_W_HI);
    short* w_l    = (short*)(ws + O_W_LO);

    // 1. qin (fp32)
    qin_kernel<<<dim3(DIMC, BATCH), 256, 0, stream>>>(x, ql_w, ql_b, qin);
    // 2. weight splits
    wsplit_kernel<<<dim3(1920), 256, 0, stream>>>(qp_w, k_w, v_w, p_w, w_h, w_l);
    // 3. qin -> qinT (transpose + split)
    tsplit_kernel<<<dim3(QPAD / 32, DIMC / 32, BATCH), 256, 0, stream>>>(qin, qinT_h, qinT_l, DIMC, NN2, QPAD);
    // 4. q = bn(1x1(qin)) -> split bf16 [b][128][196]
    gemm_split_kernel<<<dim3(2, 1, BATCH), 256, 0, stream>>>(
        w_h + 0, w_l + 0, qinT_h, qinT_l, qp_b, qp_s, qp_o,
        nullptr, q_h, q_l, 1, DIMC, NN2, QPAD);
    // 5. x -> xT (transpose + split)
    tsplit_kernel<<<dim3(XPAD / 32, DIMC / 32, BATCH), 256, 0, stream>>>(x, xT_h, xT_l, DIMC, NN, XPAD);
    // 6. k = bn(1x1(x)) -> split bf16 [b][128][784]
    gemm_split_kernel<<<dim3(7, 1, BATCH), 256, 0, stream>>>(
        w_h + 49152, w_l + 49152, xT_h, xT_l, k_b, k_s, k_o,
        nullptr, k_h, k_l, 1, DIMC, NN, XPAD);
    // 7. v = bn(1x1(x)) -> split bf16 [b][512][784]
    gemm_split_kernel<<<dim3(7, 4, BATCH), 256, 0, stream>>>(
        w_h + 98304, w_l + 98304, xT_h, xT_l, v_b, v_s, v_o,
        nullptr, v_h, v_l, 1, DIMC, NN, XPAD);
    // 8. v_local (reads split v)
    vlocal_kernel<<<dim3(DH, BATCH), 256, 0, stream>>>(v_h, v_l, vl_w, vl_b, vl_s, vl_o, vlocal);
    // 9. bias expand
    bias_expand_kernel<<<dim3((NN2 * NN + 255) / 256, HEADS), 256, 0, stream>>>(ab, bidx, biasM, n_off);
    // 10. attention -> attnT [b][196][512] fp32
    attn_mfma2_kernel<<<dim3(4, HEADS, BATCH), 256, 0, stream>>>(q_h, q_l, k_h, k_l, v_h, v_l, biasM, attnT);
    // 11. gelu(attnT + vlocal^T) -> gT hi/lo [b][256][512]
    gelu_addT_kernel<<<dim3(QPAD / 32, DH / 32, BATCH), 256, 0, stream>>>(attnT, vlocal, gT_h, gT_l);
    // 12. out = bn(1x1(g)) -> d_out fp32 [b][384][196]
    gemm_split_kernel<<<dim3(2, 3, BATCH), 256, 0, stream>>>(
        w_h + 294912, w_l + 294912, gT_h, gT_l, p_b, p_s, p_o,
        out, nullptr, nullptr, 0, DH, NN2, QPAD);
}